// Round 3
// baseline (2777.153 us; speedup 1.0000x reference)
//
#include <hip/hip_runtime.h>

// Net_87814901334404: B=512, CI=3, HW=28, K=7, C=1024, NH=16, L=12, T=17, M=B*T=8704
// Round 10 = R9 with gemm256 restructured to ONE barrier per phase (m201-style).
// R9 counters: conflicts 0 (swizzle correct) but 89.5us / MfmaUtil 24% -> the
// 2-barriers-per-phase sandwich serialized ds_read latency + 2 syncs into the
// critical path (1 block/CU, nothing else to overlap). New structure per phase:
//   { ds_reads; stage; [counted vmcnt]; s_barrier; lgkmcnt(0); MFMA }
// -> 4 barriers/K-tile (was 8); next phase's reads overlap other waves' MFMA.
// Safety rule: stage in phase p may clobber only regions last-read <= p-2
// (issue of stage_p implies all waves retired reads_{p-2} via lgkm+barrier).
// Phase order P1(0,0) P2(0,1) P3(1,1) P4(1,0); A-frags and BOTH B-frag sets
// carried in regs (P4: zero ds_reads; 24 b128/wave/tile).
// Stages: P1->Aq0(t+1) [clobbers last read p-4], P2->Bq0(t+1) [p-2],
// P3->Bq1(t+1) [p-5], P4->Aq1(t+1) [p-5]. All satisfy the rule.
// Waits: vmcnt(4) at P1 (confirms Bq1(t) for P2), P2 (confirms Aq1(t) for P3),
// P4 (confirms Aq0/Bq0(t+1) for P1'); tail: P1 vmcnt(2), P2 vmcnt(0).
// MLP now also on gemm256 (136=8x17 blocks, single round ~22us < gemm_bt 28.5).

typedef unsigned short u16;
typedef short bfrag8 __attribute__((ext_vector_type(8)));
typedef float facc4 __attribute__((ext_vector_type(4)));

__device__ __forceinline__ u16 f2bf(float f) {
  union { float f; unsigned u; } x; x.f = f;
  unsigned r = x.u + 0x7fffu + ((x.u >> 16) & 1u);   // round-to-nearest-even
  return (u16)(r >> 16);
}
__device__ __forceinline__ float bf2f(u16 h) {
  union { unsigned u; float f; } x; x.u = ((unsigned)h) << 16;
  return x.f;
}

// ---------------------------------------------------------------------------
// gemm256: out[m,n] = sum_k A[m,k]*B[n,k], bf16 in, fp32 acc. BM=BN=256, BK=64.
// Fixed geometry: M = 34*256 = 8704, N per z = 1024 (4 tiles), K = 1024.
// Grid = 8 * cpx (XCD-bijective). 512 threads = 8 waves (2M x 4N).
// LDS 128 KiB: [2 slots][A: 2qm x [128 rr][64 k] | B: 2qn x [128 rr][64 k]] u16.
// Swizzle: element at (rr, chunk c=k>>3) stored at phys slot c ^ (rr & 7);
// inverse folded into per-lane global source address (linear LDS dest).
// ---------------------------------------------------------------------------

template <int QM>
__device__ __forceinline__ void loadA(const u16* S, int sb, int aBase, int swz,
                                      bfrag8 (&aF)[4][2])
{
  const int base = sb + QM * 8192 + aBase;
#pragma unroll
  for (int im = 0; im < 4; ++im) {
    aF[im][0] = *(const bfrag8*)&S[base + im * 1024 + swz];
    aF[im][1] = *(const bfrag8*)&S[base + im * 1024 + (swz ^ 32)];
  }
}

template <int QN>
__device__ __forceinline__ void loadB(const u16* S, int sb, int bBase, int swz,
                                      bfrag8 (&bF)[2][2])
{
  const int base = sb + 16384 + QN * 8192 + bBase;
#pragma unroll
  for (int in = 0; in < 2; ++in) {
    bF[in][0] = *(const bfrag8*)&S[base + in * 1024 + swz];
    bF[in][1] = *(const bfrag8*)&S[base + in * 1024 + (swz ^ 32)];
  }
}

template <int QM, int QN>
__device__ __forceinline__ void pmfma(bfrag8 (&aF)[4][2], bfrag8 (&bF)[2][2],
                                      facc4 (&acc)[8][4])
{
#pragma unroll
  for (int im = 0; im < 4; ++im)
#pragma unroll
    for (int in = 0; in < 2; ++in) {
      facc4 c = acc[QM * 4 + im][QN * 2 + in];
      c = __builtin_amdgcn_mfma_f32_16x16x32_bf16(aF[im][0], bF[in][0], c, 0, 0, 0);
      c = __builtin_amdgcn_mfma_f32_16x16x32_bf16(aF[im][1], bF[in][1], c, 0, 0, 0);
      acc[QM * 4 + im][QN * 2 + in] = c;
    }
}

template <int MODE>
__global__ __launch_bounds__(512, 2) void gemm256(
    const u16* __restrict__ A, int lda,
    const u16* __restrict__ B0, const u16* __restrict__ B1, const u16* __restrict__ B2,
    int ldb, int K, int cpx,
    void* __restrict__ outp, long long zstride, int ldo,
    const float* __restrict__ bias)
{
  __shared__ u16 S[65536];   // 128 KiB

  const int bid = blockIdx.x;
  const int wg = (bid & 7) * cpx + (bid >> 3);     // XCD-bijective (grid % 8 == 0)
  const int perz = 34 * 4;
  const int z = wg / perz;
  const int r0 = wg - z * perz;
  const int y = r0 >> 2;                           // M-tile
  const int x = r0 & 3;                            // N-tile
  const int m0 = y * 256, n0 = x * 256;
  const u16* __restrict__ B = (z == 0) ? B0 : ((z == 1) ? B1 : B2);

  const int tid = threadIdx.x;
  const int wave = tid >> 6;
  const int lane = tid & 63;
  const int lrow = lane & 15, lquad = lane >> 4;
  const int mh = wave >> 2;                        // wave m-half (0..1)
  const int w4 = wave & 3;                         // wave n-quarter (0..3)
  const int wm = mh * 128, wn = w4 * 64;

  // consumer LDS offsets (elements)
  const int swz = (lquad ^ (lrow & 7)) * 8;        // chunk kk=0; ^32 for kk=1
  const int aBase = mh * 4096 + lrow * 64;
  const int bBase = w4 * 2048 + lrow * 64;

  // staging: lane-slot p = wave*128 + h*64 + lane -> rr = wave*16 + h*8 + (lane>>3),
  // phys slot = lane&7, content chunk kc = (lane&7) ^ (lane>>3).
  const int l3 = lane >> 3;
  const int kc = ((lane & 7) ^ l3) * 8;            // element offset in k-tile
  const int arow0 = mh * 128 + (wave & 3) * 16 + l3;       // h=0 (+ qm*64)
  const int arow1 = arow0 + 8;                              // h=1
  const int w20 = wave * 2, w21 = wave * 2 + 1;
  const int brow0 = (w20 >> 2) * 64 + (w20 & 3) * 8 + l3;  // h=0 (+ qn*32)
  const int brow1 = (w21 >> 2) * 64 + (w21 & 3) * 8 + l3;  // h=1
  const u16* gA0 = A + (long long)(m0 + arow0) * lda + kc;
  const u16* gA1 = A + (long long)(m0 + arow1) * lda + kc;
  const u16* gB0 = B + (long long)(n0 + brow0) * ldb + kc;
  const u16* gB1 = B + (long long)(n0 + brow1) * ldb + kc;
  const long long aq = 64LL * lda;                 // qm=1 row offset
  const long long bq = 32LL * ldb;                 // qn=1 n offset
  const int ldsW = wave * 1024 + lane * 8;         // linear dest (lane*16B)

  auto stageA = [&](int qm, int tt) {
    u16* d0 = S + ((tt & 1) * 32768 + qm * 8192) + ldsW;
    __builtin_amdgcn_global_load_lds((const __attribute__((address_space(1))) void*)(gA0 + qm * aq + tt * 64),
                                     (__attribute__((address_space(3))) void*)d0, 16, 0, 0);
    __builtin_amdgcn_global_load_lds((const __attribute__((address_space(1))) void*)(gA1 + qm * aq + tt * 64),
                                     (__attribute__((address_space(3))) void*)(d0 + 512), 16, 0, 0);
  };
  auto stageB = [&](int qn, int tt) {
    u16* d0 = S + ((tt & 1) * 32768 + 16384 + qn * 8192) + ldsW;
    __builtin_amdgcn_global_load_lds((const __attribute__((address_space(1))) void*)(gB0 + qn * bq + tt * 64),
                                     (__attribute__((address_space(3))) void*)d0, 16, 0, 0);
    __builtin_amdgcn_global_load_lds((const __attribute__((address_space(1))) void*)(gB1 + qn * bq + tt * 64),
                                     (__attribute__((address_space(3))) void*)(d0 + 512), 16, 0, 0);
  };

  facc4 acc[8][4] = {};

  // prologue: tile0 regions in steady-state order A0,B0,B1,A1; confirm A0,B0.
  stageA(0, 0); stageB(0, 0); stageB(1, 0); stageA(1, 0);
  asm volatile("s_waitcnt vmcnt(4)" ::: "memory");
  __builtin_amdgcn_sched_barrier(0);
  __builtin_amdgcn_s_barrier();

  const int NT = K >> 6;
  bfrag8 aF[4][2], b0[2][2], b1[2][2];
  for (int t = 0; t < NT; ++t) {
    const int sb = (t & 1) * 32768;
    const bool more = (t + 1 < NT);
    { // P1 (0,0): read Aq0->aF, Bq0->b0; stage Aq0(t+1); confirm Bq1(t)
      loadA<0>(S, sb, aBase, swz, aF);
      loadB<0>(S, sb, bBase, swz, b0);
      if (more) stageA(0, t + 1);
      if (more) asm volatile("s_waitcnt vmcnt(4)" ::: "memory");
      else      asm volatile("s_waitcnt vmcnt(2)" ::: "memory");
      __builtin_amdgcn_sched_barrier(0);
      __builtin_amdgcn_s_barrier();
      asm volatile("s_waitcnt lgkmcnt(0)" ::: "memory");
      __builtin_amdgcn_sched_barrier(0);
      __builtin_amdgcn_s_setprio(1);
      pmfma<0, 0>(aF, b0, acc);
      __builtin_amdgcn_s_setprio(0);
    }
    { // P2 (0,1): read Bq1->b1; stage Bq0(t+1); confirm Aq1(t)
      loadB<1>(S, sb, bBase, swz, b1);
      if (more) stageB(0, t + 1);
      if (more) asm volatile("s_waitcnt vmcnt(4)" ::: "memory");
      else      asm volatile("s_waitcnt vmcnt(0)" ::: "memory");
      __builtin_amdgcn_sched_barrier(0);
      __builtin_amdgcn_s_barrier();
      asm volatile("s_waitcnt lgkmcnt(0)" ::: "memory");
      __builtin_amdgcn_sched_barrier(0);
      __builtin_amdgcn_s_setprio(1);
      pmfma<0, 1>(aF, b1, acc);
      __builtin_amdgcn_s_setprio(0);
    }
    { // P3 (1,1): read Aq1->aF; stage Bq1(t+1); no wait
      loadA<1>(S, sb, aBase, swz, aF);
      if (more) stageB(1, t + 1);
      __builtin_amdgcn_sched_barrier(0);
      __builtin_amdgcn_s_barrier();
      asm volatile("s_waitcnt lgkmcnt(0)" ::: "memory");
      __builtin_amdgcn_sched_barrier(0);
      __builtin_amdgcn_s_setprio(1);
      pmfma<1, 1>(aF, b1, acc);
      __builtin_amdgcn_s_setprio(0);
    }
    { // P4 (1,0): no reads (b0 carried); stage Aq1(t+1); confirm Aq0/Bq0(t+1)
      if (more) stageA(1, t + 1);
      if (more) asm volatile("s_waitcnt vmcnt(4)" ::: "memory");
      __builtin_amdgcn_sched_barrier(0);
      __builtin_amdgcn_s_barrier();
      __builtin_amdgcn_s_setprio(1);
      pmfma<1, 0>(aF, b0, acc);
      __builtin_amdgcn_s_setprio(0);
    }
  }

  // epilogue: C/D layout col=lane&15, row=lquad*4+reg (m89/m91)
#pragma unroll
  for (int in = 0; in < 4; ++in) {
    const int col = n0 + wn + in * 16 + lrow;
    const float bb = bias ? bias[col] : 0.0f;
#pragma unroll
    for (int im = 0; im < 8; ++im) {
#pragma unroll
      for (int r = 0; r < 4; ++r) {
        const int row = m0 + wm + im * 16 + lquad * 4 + r;
        const float v = acc[im][in][r] + bb;
        if (MODE == 1) {
          (((u16*)outp) + zstride * z)[(long long)row * ldo + col] = f2bf(v);
        } else if (MODE == 2) {
          ((float*)outp)[(long long)row * ldo + col] += v;
        } else {  // MODE 4
          const long long off = (long long)row * ldo + col;
          const float nv = ((float*)outp)[off] + v;
          ((float*)outp)[off] = nv;
          ((u16*)zstride)[off] = f2bf(nv);
        }
      }
    }
  }
}

// ---------------------------------------------------------------------------
// GEMM (R3/R7 128^2 structure): out[m,n] = sum_k A[m,k]*B[n,k]. Used for the
// first conv GEMM (K=192), decode scatter, and the small-ws fallback.
// ---------------------------------------------------------------------------
template <int MODE>
__global__ __launch_bounds__(256) void gemm_bt(
    const u16* __restrict__ A, int lda,
    const u16* __restrict__ B0, const u16* __restrict__ B1, const u16* __restrict__ B2,
    int ldb, int K, int NX,
    void* __restrict__ outp, long long zstride, int ldo,
    const float* __restrict__ bias)
{
  __shared__ __align__(16) u16 As[8192];   // 16KB: [t][128][32]
  __shared__ __align__(16) u16 Bs[8192];   // 16KB

  const int l = blockIdx.x;
  const int xcd = l & 7;
  const int j = l >> 3;
  const int per_epoch = 9 * NX;
  const int z = j / per_epoch;
  const int r2 = j - z * per_epoch;
  const int g = r2 / NX;
  const int y = xcd + 8 * g;
  if (y >= 68) return;                      // dead block (uniform) — exits before barriers
  const int x = r2 - g * NX;
  const int n0 = x * 128;
  const int m0 = y * 128;
  const u16* __restrict__ B = (z == 0) ? B0 : ((z == 1) ? B1 : B2);

  const int tid  = threadIdx.x;
  const int wave = tid >> 6;
  const int lane = tid & 63;
  const int wm   = (wave >> 1) * 64;
  const int wn   = (wave & 1) * 64;
  const int lrow = lane & 15;
  const int lquad = lane >> 4;

  facc4 acc[4][4] = {};

  const u16* ga[4]; const u16* gb[4];
#pragma unroll
  for (int j2 = 0; j2 < 4; ++j2) {
    const int s = tid + 256 * j2;
    const int t = s >> 9, s2 = s & 511;
    const int r = s2 >> 2, c = (s2 & 3) + 4 * t;
    ga[j2] = A + (long long)(m0 + r) * lda + c * 8;
    gb[j2] = B + (long long)(n0 + r) * ldb + c * 8;
  }

  const int aoff = (wm + lrow) * 32 + lquad * 8;
  const int boff = (wn + lrow) * 32 + lquad * 8;

  for (int k0 = 0; k0 < K; k0 += 64) {
#pragma unroll
    for (int j2 = 0; j2 < 4; ++j2) {
      __builtin_amdgcn_global_load_lds((const __attribute__((address_space(1))) void*)ga[j2],
                                       (__attribute__((address_space(3))) void*)(As + (tid + 256 * j2) * 8), 16, 0, 0);
      __builtin_amdgcn_global_load_lds((const __attribute__((address_space(1))) void*)gb[j2],
                                       (__attribute__((address_space(3))) void*)(Bs + (tid + 256 * j2) * 8), 16, 0, 0);
      ga[j2] += 64; gb[j2] += 64;
    }
    __syncthreads();

#pragma unroll
    for (int t = 0; t < 2; ++t) {
      bfrag8 af[4], bfr[4];
#pragma unroll
      for (int im = 0; im < 4; ++im) af[im] = *(const bfrag8*)(As + t * 4096 + aoff + 512 * im);
#pragma unroll
      for (int in = 0; in < 4; ++in) bfr[in] = *(const bfrag8*)(Bs + t * 4096 + boff + 512 * in);
#pragma unroll
      for (int im = 0; im < 4; ++im)
#pragma unroll
        for (int in = 0; in < 4; ++in)
          acc[im][in] = __builtin_amdgcn_mfma_f32_16x16x32_bf16(af[im], bfr[in], acc[im][in], 0, 0, 0);
    }
    __syncthreads();
  }

#pragma unroll
  for (int in = 0; in < 4; ++in) {
    const int col = n0 + wn + in * 16 + lrow;
    const float bb = bias ? bias[col] : 0.0f;
#pragma unroll
    for (int im = 0; im < 4; ++im) {
#pragma unroll
      for (int r = 0; r < 4; ++r) {
        const int row = m0 + wm + im * 16 + lquad * 4 + r;
        const float v = acc[im][in][r] + bb;
        if (MODE == 0) {
          ((float*)outp)[(long long)row * ldo + col] = v;
        } else if (MODE == 1) {
          (((u16*)outp) + zstride * z)[(long long)row * ldo + col] = f2bf(v);
        } else if (MODE == 2) {
          ((float*)outp)[(long long)row * ldo + col] += v;
        } else if (MODE == 4) {
          const long long off = (long long)row * ldo + col;
          const float nv = ((float*)outp)[off] + v;
          ((float*)outp)[off] = nv;
          ((u16*)zstride)[off] = f2bf(nv);
        } else {  // MODE 3: deconv scatter. row=b*17+s, col=d*49+hk*7+wk (<147)
          if (col < 147) {
            const int b = row / 17, s = row - b * 17;
            const int d = col / 49, rem = col - d * 49;
            const int hk = rem / 7, wk = rem - hk * 7;
            ((float*)outp)[(long long)((b * 3 + d) * 7 + hk) * 119 + s * 7 + wk] = v;
          }
        }
      }
    }
  }
}

// ---------------------------------------------------------------------------
// LayerNorm over C=1024: fp32 h row -> bf16 normalized row. float4/ushort4.
// ---------------------------------------------------------------------------
__global__ __launch_bounds__(256) void ln_kernel(
    const float* __restrict__ h, const float* __restrict__ w,
    const float* __restrict__ b, u16* __restrict__ out)
{
  const long long row = blockIdx.x;
  const int t = threadIdx.x;
  const float4 v = ((const float4*)(h + row * 1024))[t];
  float s = v.x + v.y + v.z + v.w;
  float q = v.x * v.x + v.y * v.y + v.z * v.z + v.w * v.w;
  for (int o = 32; o > 0; o >>= 1) { s += __shfl_down(s, o); q += __shfl_down(q, o); }
  __shared__ float ss[4], sq[4];
  const int wave = t >> 6, lane = t & 63;
  if (lane == 0) { ss[wave] = s; sq[wave] = q; }
  __syncthreads();
  const float st = ss[0] + ss[1] + ss[2] + ss[3];
  const float qt = sq[0] + sq[1] + sq[2] + sq[3];
  const float mean = st * (1.0f / 1024.0f);
  const float var = qt * (1.0f / 1024.0f) - mean * mean;
  const float inv = rsqrtf(var + 1e-5f);
  const float4 w4 = ((const float4*)w)[t];
  const float4 b4 = ((const float4*)b)[t];
  ushort4 o;
  o.x = f2bf((v.x - mean) * inv * w4.x + b4.x);
  o.y = f2bf((v.y - mean) * inv * w4.y + b4.y);
  o.z = f2bf((v.z - mean) * inv * w4.z + b4.z);
  o.w = f2bf((v.w - mean) * inv * w4.w + b4.w);
  ((ushort4*)(out + row * 1024))[t] = o;
}

// ---------------------------------------------------------------------------
// Causal attention, T=17, hd=64. One block per (batch, head). h += attn out.
// ---------------------------------------------------------------------------
__global__ __launch_bounds__(256) void attn_kernel(const u16* __restrict__ QKV,
                                                   float* __restrict__ h)
{
  const int blk = blockIdx.x;          // 0..8191
  const int b = blk >> 4, head = blk & 15;
  __shared__ float qs[17][64], ks[17][64], vs[17][64];
  __shared__ float sc[17][20];
  const long long base = (long long)b * 17408 + head * 64;   // 17*1024
  const u16* Q  = QKV;
  const u16* Kp = QKV + 8912896LL;       // 8704*1024
  const u16* V  = QKV + 17825792LL;
  const int tid = threadIdx.x;

  if (tid < 136) {                        // 17 rows x 8 chunks of 8 bf16
    const int t = tid >> 3, dg = (tid & 7) * 8;
    const long long off = base + (long long)t * 1024 + dg;
    union { uint4 u; u16 s[8]; } xq, xk, xv;
    xq.u = *(const uint4*)(Q + off);
    xk.u = *(const uint4*)(Kp + off);
    xv.u = *(const uint4*)(V + off);
#pragma unroll
    for (int j = 0; j < 8; ++j) {
      qs[t][dg + j] = bf2f(xq.s[j]);
      ks[t][dg + j] = bf2f(xk.s[j]);
      vs[t][dg + j] = bf2f(xv.s[j]);
    }
  }
  __syncthreads();

  for (int i = tid; i < 289; i += 256) {
    const int tq = i / 17, tk = i % 17;
    float a = 0.0f;
    if (tk <= tq) {
#pragma unroll
      for (int d = 0; d < 64; ++d) a += qs[tq][d] * ks[tk][d];
      a *= 0.125f;                     // 1/sqrt(64)
    }
    sc[tq][tk] = a;
  }
  __syncthreads();

  if (tid < 17) {
    const int tq = tid;
    float m = -1e30f;
    for (int tk = 0; tk <= tq; ++tk) m = fmaxf(m, sc[tq][tk]);
    float s = 0.0f;
    for (int tk = 0; tk <= tq; ++tk) { const float e = __expf(sc[tq][tk] - m); sc[tq][tk] = e; s += e; }
    const float inv = 1.0f / s;
    for (int tk = 0; tk <= tq; ++tk) sc[tq][tk] *= inv;
  }
  __syncthreads();

  for (int i = tid; i < 272; i += 256) {  // 17 rows x 16 float4 groups (loop!)
    const int tq = i >> 4, dg = (i & 15) * 4;
    float o0 = 0, o1 = 0, o2 = 0, o3 = 0;
    for (int tk = 0; tk <= tq; ++tk) {
      const float s = sc[tq][tk];
      o0 += s * vs[tk][dg];     o1 += s * vs[tk][dg + 1];
      o2 += s * vs[tk][dg + 2]; o3 += s * vs[tk][dg + 3];
    }
    float4* hp = (float4*)(h + base + (long long)tq * 1024 + dg);
    float4 hv = *hp;
    hv.x += o0; hv.y += o1; hv.z += o2; hv.w += o3;
    *hp = hv;                             // exclusive owner of this slice
  }
}

// ---------------------------------------------------------------------------
// Build patch matrix P bf16 [8704][192]; t=0 thumb = 2x2 avg (bilinear scale-4
// half-pixel), t=1+s patch; cols 147..191 zero-pad (K padded to 192).
// ---------------------------------------------------------------------------
__global__ void build_p(const float* __restrict__ x, u16* __restrict__ P)
{
  const int n = blockIdx.x;
  const int j = threadIdx.x;
  if (j >= 192) return;
  const int b = n / 17, t = n % 17;
  float val = 0.0f;
  if (j < 147) {
    const int c = j / 49, rem = j % 49, p = rem / 7, q = rem % 7;
    const float* xb = x + (long long)(b * 3 + c) * 784;
    if (t == 0) {
      const int r = 4 * p + 1, cc = 4 * q + 1;
      val = 0.25f * (xb[r * 28 + cc] + xb[r * 28 + cc + 1] +
                     xb[(r + 1) * 28 + cc] + xb[(r + 1) * 28 + cc + 1]);
    } else {
      const int s = t - 1, ii = s >> 2, jj = s & 3;
      val = xb[(7 * ii + p) * 28 + 7 * jj + q];
    }
  }
  P[(long long)n * 192 + j] = f2bf(val);
}

// conv_w fp32 [1024][147] -> Wc bf16 [1024][192] (zero-pad K to 192) and
// cw2 bf16 [256][1024]: cw2[j][c] = conv_w[c*147+j], rows 147..255 zero.
__global__ __launch_bounds__(256) void cvt_conv(const float* __restrict__ cw,
                                                u16* __restrict__ Wc, u16* __restrict__ cw2)
{
  const int i = blockIdx.x * 256 + threadIdx.x;     // grid covers 196608 + 262144
  if (i < 196608) {
    const int d = i / 192, j = i % 192;
    Wc[i] = (j < 147) ? f2bf(cw[d * 147 + j]) : (u16)0;
  } else {
    const int i2 = i - 196608;
    if (i2 < 262144) {
      const int j = i2 / 1024, c = i2 % 1024;
      cw2[i2] = (j < 147) ? f2bf(cw[c * 147 + j]) : (u16)0;
    }
  }
}

// W'[j][k] = sum_c cw2[j][c] * outw[c][k]  (fused out-proj+deconv weight).
__global__ __launch_bounds__(256) void wprime_kernel(
    const u16* __restrict__ cw2, const float* __restrict__ outw,
    u16* __restrict__ Wp)
{
  const int k = blockIdx.x * 256 + threadIdx.x;
  const int j = blockIdx.y;
  float a = 0.0f;
  for (int c = 0; c < 1024; ++c)
    a += bf2f(cw2[j * 1024 + c]) * outw[c * 1024 + k];
  Wp[j * 1024 + k] = f2bf(a);
}

// b'[j] = sum_c outb[c] * cw2[j][c]. One block, 256 threads.
__global__ __launch_bounds__(256) void bprime_kernel(
    const u16* __restrict__ cw2, const float* __restrict__ outb,
    float* __restrict__ bp)
{
  const int j = threadIdx.x;
  float a = 0.0f;
  for (int c = 0; c < 1024; ++c) a += outb[c] * bf2f(cw2[j * 1024 + c]);
  bp[j] = a;
}

// Bulk weight convert: 49 x 1M fp32 -> bf16.
__global__ __launch_bounds__(256) void cvt_all(
    const float* __restrict__ wq, const float* __restrict__ wk,
    const float* __restrict__ wv, const float* __restrict__ mlpw,
    const float* __restrict__ outw, u16* __restrict__ wAll)
{
  const int i = blockIdx.x * 256 + threadIdx.x;    // float4 index, < 12,845,056
  const int which = i >> 18;                        // 0..48
  const int off = i & 262143;
  const float4* src;
  if (which < 48) {
    const int layer = which >> 2, sub = which & 3;
    const float* base = (sub == 0) ? wq : (sub == 1) ? wk : (sub == 2) ? wv : mlpw;
    src = (const float4*)(base + (size_t)layer * 1048576) + off;
  } else {
    src = (const float4*)outw + off;
  }
  const float4 v = *src;
  ushort4 o; o.x = f2bf(v.x); o.y = f2bf(v.y); o.z = f2bf(v.z); o.w = f2bf(v.w);
  *(ushort4*)(wAll + (size_t)which * 1048576 + (size_t)off * 4) = o;
}

// per-layer weight cast fallback (small ws): wq,wk,wv -> o3[3][1M], mlp -> om.
__global__ __launch_bounds__(256) void cvt4(const float* __restrict__ a0, const float* __restrict__ a1,
                                            const float* __restrict__ a2, const float* __restrict__ a3,
                                            u16* __restrict__ o3, u16* __restrict__ om)
{
  const int i = blockIdx.x * 256 + threadIdx.x;
  const int which = i >> 20, off = i & 1048575;
  const float* src = (which == 0) ? a0 : (which == 1) ? a1 : (which == 2) ? a2 : a3;
  const float v = src[off];
  if (which < 3) o3[which * 1048576 + off] = f2bf(v);
  else           om[off] = f2bf(v);
}

__global__ __launch_bounds__(256) void cvtN(const float* __restrict__ in, u16* __restrict__ out, int n)
{
  const int i = blockIdx.x * 256 + threadIdx.x;
  if (i < n) out[i] = f2bf(in[i]);
}

// ---------------------------------------------------------------------------
extern "C" void kernel_launch(void* const* d_in, const int* in_sizes, int n_in,
                              void* d_out, int out_size, void* d_ws, size_t ws_size,
                              hipStream_t stream)
{
  const float* x     = (const float*)d_in[0];
  const float* convw = (const float*)d_in[1];
  const float* ln1w  = (const float*)d_in[2];
  const float* ln1b  = (const float*)d_in[3];
  const float* wq    = (const float*)d_in[4];
  const float* wk    = (const float*)d_in[5];
  const float* wv    = (const float*)d_in[6];
  const float* ln2w  = (const float*)d_in[7];
  const float* ln2b  = (const float*)d_in[8];
  const float* mlpw  = (const float*)d_in[9];
  const float* mlpb  = (const float*)d_in[10];
  const float* outw  = (const float*)d_in[11];
  const float* outb  = (const float*)d_in[12];

  char* w = (char*)d_ws;
  const bool big = (ws_size >= 214500352ULL);

  // old-kernel grid sizes: 8 xcd * NZ * 9 groups * NX
  const int G_QKV = 8 * 3 * 9 * 8;   // 1728 (fallback path)
  const int G_ONE = 8 * 1 * 9 * 8;   // 576
  const int G_DEC = 8 * 1 * 9 * 2;   // 144

  if (big) {
    float* h   = (float*)(w);                   // 35,651,584 B
    u16* Abuf  = (u16*)(w + 35651584);          // 17,825,792 B
    u16* QKV   = (u16*)(w + 53477376);          // 53,477,376 B (dead after last attn
                                                //   -> reused as bf16 h-shadow)
    u16* wAll  = (u16*)(w + 106954752);         // 102,760,448 B (49 x 1M bf16)
    u16* Wc    = (u16*)(w + 209715200);         //    393,216 B
    u16* cw2   = (u16*)(w + 210108416);         //    524,288 B
    u16* P     = (u16*)(w + 210632704);         //  3,342,336 B
    u16* Wp    = (u16*)(w + 213975040);         //    524,288 B
    float* bp  = (float*)(w + 214499328);       //      1,024 B -> 214,500,352

    cvt_all<<<50176, 256, 0, stream>>>(wq, wk, wv, mlpw, outw, wAll);
    cvt_conv<<<1792, 256, 0, stream>>>(convw, Wc, cw2);
    wprime_kernel<<<dim3(4, 256), 256, 0, stream>>>(cw2, outw, Wp);
    bprime_kernel<<<1, 256, 0, stream>>>(cw2, outb, bp);
    build_p<<<8704, 192, 0, stream>>>(x, P);
    gemm_bt<0><<<G_ONE, 256, 0, stream>>>(P, 192, Wc, Wc, Wc, 192, 192, 8,
                                          (void*)h, 0LL, 1024, nullptr);
    for (int l = 0; l < 12; ++l) {
      u16* wl = wAll + (size_t)l * 4194304;
      ln_kernel<<<8704, 256, 0, stream>>>(h, ln1w + l * 1024, ln1b + l * 1024, Abuf);
      // QKV: 34 M-tiles x 4 N-tiles x 3 weights = 408 blocks = 8*51
      gemm256<1><<<408, 512, 0, stream>>>(Abuf, 1024, wl, wl + 1048576, wl + 2097152,
                                          1024, 1024, 51, (void*)QKV, 8912896LL, 1024, nullptr);
      attn_kernel<<<8192, 256, 0, stream>>>(QKV, h);
      ln_kernel<<<8704, 256, 0, stream>>>(h, ln2w + l * 1024, ln2b + l * 1024, Abuf);
      // MLP: 34 x 4 = 136 blocks = 8*17
      if (l < 11) {
        gemm256<2><<<136, 512, 0, stream>>>(Abuf, 1024, wl + 3145728, wl + 3145728, wl + 3145728,
                                            1024, 1024, 17, (void*)h, 0LL, 1024, mlpb + l * 1024);
      } else {  // last MLP: h += v AND bf16 shadow into QKV (dead; NOT an input)
        gemm256<4><<<136, 512, 0, stream>>>(Abuf, 1024, wl + 3145728, wl + 3145728, wl + 3145728,
                                            1024, 1024, 17, (void*)h,
                                            (long long)(uintptr_t)QKV, 1024,
                                            mlpb + l * 1024);
      }
    }
    // fused out-proj+decode: d_out = scatter(h_bf16 @ W'^T + b')
    gemm_bt<3><<<G_DEC, 256, 0, stream>>>(QKV, 1024, Wp, Wp, Wp,
                                          1024, 1024, 2, d_out, 0LL, 0, bp);
  } else {
    if (ws_size < 119603200ULL) return;
    float* h   = (float*)(w);
    u16* Abuf  = (u16*)(w + 35651584);
    u16* QKV   = (u16*)(w + 53477376);
    u16* wb3   = (u16*)(w + 106954752);          // 6,291,456
    u16* wmb   = (u16*)(w + 113246208);          // 2,097,152
    u16* Wc    = (u16*)(w + 115343360);          //   393,216
    u16* cw2   = (u16*)(w + 115736576);          //   524,288
    u16* P     = (u16*)(w + 116260864);          // 3,342,336 -> 119,603,200

    cvt_conv<<<1792, 256, 0, stream>>>(convw, Wc, cw2);
    build_p<<<8704, 192, 0, stream>>>(x, P);
    gemm_bt<0><<<G_ONE, 256, 0, stream>>>(P, 192, Wc, Wc, Wc, 192, 192, 8,
                                          (void*)h, 0LL, 1024, nullptr);
    for (int l = 0; l < 12; ++l) {
      const size_t wo = (size_t)l * 1048576;
      cvt4<<<16384, 256, 0, stream>>>(wq + wo, wk + wo, wv + wo, mlpw + wo, wb3, wmb);
      ln_kernel<<<8704, 256, 0, stream>>>(h, ln1w + l * 1024, ln1b + l * 1024, Abuf);
      gemm_bt<1><<<G_QKV, 256, 0, stream>>>(Abuf, 1024, wb3, wb3 + 1048576, wb3 + 2097152,
                                            1024, 1024, 8, (void*)QKV, 8912896LL, 1024, nullptr);
      attn_kernel<<<8192, 256, 0, stream>>>(QKV, h);
      ln_kernel<<<8704, 256, 0, stream>>>(h, ln2w + l * 1024, ln2b + l * 1024, Abuf);
      gemm_bt<2><<<G_ONE, 256, 0, stream>>>(Abuf, 1024, wmb, wmb, wmb,
                                            1024, 1024, 8, (void*)h, 0LL, 1024, mlpb + l * 1024);
    }
    cvtN<<<34816, 256, 0, stream>>>(h, Abuf, 8912896);
    cvtN<<<4096, 256, 0, stream>>>(outw, wmb, 1048576);
    gemm_bt<1><<<G_ONE, 256, 0, stream>>>(Abuf, 1024, wmb, wmb, wmb,
                                          1024, 1024, 8, (void*)QKV, 0LL, 1024, outb);
    gemm_bt<3><<<G_DEC, 256, 0, stream>>>(QKV, 1024, cw2, cw2, cw2,
                                          1024, 1024, 2, d_out, 0LL, 0, nullptr);
  }
}

// Round 4
// 2681.021 us; speedup vs baseline: 1.0359x; 1.0359x over previous
//
#include <hip/hip_runtime.h>

// Net_87814901334404: B=512, CI=3, HW=28, K=7, C=1024, NH=16, L=12, T=17, M=B*T=8704
// Round 11: gemm256 rebuilt as barrier-free-within-tile, 3-slot LDS pipeline.
// R10 analysis: per K-tile MFMA ~2062cy and LDS pipe ~2048cy are balanced, but
// 4-barrier lockstep phases SERIALIZED them (5900cy/tile, MfmaUtil 27%).
// New per-tile: {12 ds_read (all quadrant frags) ; 4 global_load_lds (t+2) ;
// 32 MFMA (compiler inserts counted lgkm per frag; DS retires in-order) ;
// vmcnt(4) ; s_barrier}. 3 slots (96KB): reads hit slot t%3, stages write
// (t+2)%3 -> no intra-tile hazard, 1 barrier/tile, no lgkm(0) drains, stage
// confirmed a full tile after issue. BK=32 -> frag regs A0/A1/B0/B1 = 48 VGPR.
// LDS layout: per region [64 lines][8 slots of 16B]; (rr,c) at line rr>>1,
// slot (c + 4*(rr&1)) ^ (line&7) -> banks depend on slot only -> 2-way max on
// ds_read_b128 AND linear gload writes. Inverse folded into global src addr.
// Clobber audit: stage(t+2) writes slot last READ in tile t-1; all tile t-1
// reads retire before its end barrier (in-order DS). vmcnt invariant: <=4
// outstanding at tile start; +4 issued; vmcnt(4) at end confirms stage(t+1).
// MLP back on gemm_bt (R10 data: MLP-on-gemm256 ~40us vs gemm_bt 28.5us).

typedef unsigned short u16;
typedef short bfrag8 __attribute__((ext_vector_type(8)));
typedef float facc4 __attribute__((ext_vector_type(4)));

__device__ __forceinline__ u16 f2bf(float f) {
  union { float f; unsigned u; } x; x.f = f;
  unsigned r = x.u + 0x7fffu + ((x.u >> 16) & 1u);   // round-to-nearest-even
  return (u16)(r >> 16);
}
__device__ __forceinline__ float bf2f(u16 h) {
  union { unsigned u; float f; } x; x.u = ((unsigned)h) << 16;
  return x.f;
}

// ---------------------------------------------------------------------------
// gemm256: out[m,n] = sum_k A[m,k]*B[n,k], bf16 in, fp32 acc. BM=BN=256, BK=32.
// M = 34*256 = 8704, N per z = 1024 (4 tiles), K % 32 == 0 (NT >= 2).
// Grid = 8*cpx XCD-bijective. 512 thr = 8 waves (2M x 4N), wave out 128x64.
// LDS 96KB: 3 slots x [Aq0 4096 | Aq1 4096 | Bq0 4096 | Bq1 4096] u16.
// A-region qm: rr=(mh<<6)|j -> row mh*128+qm*64+j. B qn: rr=(w4<<5)|j -> col
// w4*64+qn*32+j. Element (rr, c=k>>3) at line rr>>1, slot (c+4*(rr&1))^(line&7).
// MODE 1: bf16 out at (u16*)outp+z*zstride; 2: f32 +=; 4: f32 += AND bf16 shadow.
// ---------------------------------------------------------------------------

template <int MODE>
__global__ __launch_bounds__(512, 2) void gemm256(
    const u16* __restrict__ A, int lda,
    const u16* __restrict__ B0, const u16* __restrict__ B1, const u16* __restrict__ B2,
    int ldb, int K, int cpx,
    void* __restrict__ outp, long long zstride, int ldo,
    const float* __restrict__ bias)
{
  __shared__ u16 S[49152];   // 96 KiB

  const int bid = blockIdx.x;
  const int wg = (bid & 7) * cpx + (bid >> 3);     // XCD-bijective (grid % 8 == 0)
  const int perz = 34 * 4;
  const int z = wg / perz;
  const int r0 = wg - z * perz;
  const int y = r0 >> 2;                           // M-tile
  const int x = r0 & 3;                            // N-tile
  const int m0 = y * 256, n0 = x * 256;
  const u16* __restrict__ B = (z == 0) ? B0 : ((z == 1) ? B1 : B2);

  const int tid = threadIdx.x;
  const int wave = tid >> 6;
  const int lane = tid & 63;
  const int lrow = lane & 15, lquad = lane >> 4;
  const int mh = wave >> 2;                        // wave m-half (0..1)
  const int w4 = wave & 3;                         // wave n-quarter (0..3)
  const int wm = mh * 128, wn = w4 * 64;

  // consumer ds_read offsets (elements within a region)
  int offA[4], offB[2];
#pragma unroll
  for (int im = 0; im < 4; ++im) {
    const int rr = mh * 64 + im * 16 + lrow;
    const int l = rr >> 1;
    const int s = (lquad + 4 * (rr & 1)) ^ (l & 7);
    offA[im] = l * 64 + s * 8;
  }
#pragma unroll
  for (int in = 0; in < 2; ++in) {
    const int rr = w4 * 32 + in * 16 + lrow;
    const int l = rr >> 1;
    const int s = (lquad + 4 * (rr & 1)) ^ (l & 7);
    offB[in] = l * 64 + s * 8;
  }

  // staging: wave -> region r=wave>>1 (0=Aq0,1=Aq1,2=Bq0,3=Bq1), half hh=wave&1.
  // instr i covers phys chunks p = hh*256 + i*64 + lane; logical (rrs,cs) from
  // inverse swizzle; source addr pre-swizzled, LDS dest linear (lane*16B).
  const int rgn = wave >> 1;
  const int hh = wave & 1;
  const u16* gsrc[4];
  int gdst[4];
#pragma unroll
  for (int i = 0; i < 4; ++i) {
    const int p = hh * 256 + i * 64 + lane;
    const int l = p >> 3, s = p & 7;
    const int v = s ^ (l & 7);
    const int rrs = 2 * l + (v >> 2);
    const int cs = v & 3;
    if (rgn < 2) {
      const int grow = m0 + (rrs >> 6) * 128 + rgn * 64 + (rrs & 63);
      gsrc[i] = A + (long long)grow * lda + cs * 8;
    } else {
      const int gcol = n0 + (rrs >> 5) * 64 + (rgn - 2) * 32 + (rrs & 31);
      gsrc[i] = B + (long long)gcol * ldb + cs * 8;
    }
    gdst[i] = rgn * 4096 + p * 8;
  }

  facc4 acc[8][4] = {};

  // prologue: stage tile0 -> slot0, tile1 -> slot1; confirm tile0 (vmcnt(4)).
#pragma unroll
  for (int i = 0; i < 4; ++i) {
    __builtin_amdgcn_global_load_lds((const __attribute__((address_space(1))) void*)gsrc[i],
                                     (__attribute__((address_space(3))) void*)(S + gdst[i]), 16, 0, 0);
    gsrc[i] += 32;
  }
#pragma unroll
  for (int i = 0; i < 4; ++i) {
    __builtin_amdgcn_global_load_lds((const __attribute__((address_space(1))) void*)gsrc[i],
                                     (__attribute__((address_space(3))) void*)(S + 16384 + gdst[i]), 16, 0, 0);
    gsrc[i] += 32;
  }
  asm volatile("s_waitcnt vmcnt(4)" ::: "memory");
  __builtin_amdgcn_sched_barrier(0);
  __builtin_amdgcn_s_barrier();
  __builtin_amdgcn_sched_barrier(0);

  const int NT = K >> 5;
  int sb0 = 0, sb1 = 16384, sb2 = 32768;   // read slot, next, write slot (t+2)

  for (int t = 0; t < NT; ++t) {
    bfrag8 a0[4], a1[4], bf0[2], bf1[2];
    // issue all 12 ds_reads of tile t (slot sb0), in quadrant-consumption order
#pragma unroll
    for (int im = 0; im < 4; ++im) a0[im] = *(const bfrag8*)&S[sb0 + offA[im]];
#pragma unroll
    for (int in = 0; in < 2; ++in) bf0[in] = *(const bfrag8*)&S[sb0 + 8192 + offB[in]];
#pragma unroll
    for (int in = 0; in < 2; ++in) bf1[in] = *(const bfrag8*)&S[sb0 + 12288 + offB[in]];
#pragma unroll
    for (int im = 0; im < 4; ++im) a1[im] = *(const bfrag8*)&S[sb0 + 4096 + offA[im]];
    // stage tile t+2 into slot sb2 (distinct from read slot; hazard-free)
    if (t + 2 < NT) {
#pragma unroll
      for (int i = 0; i < 4; ++i) {
        __builtin_amdgcn_global_load_lds((const __attribute__((address_space(1))) void*)gsrc[i],
                                         (__attribute__((address_space(3))) void*)(S + sb2 + gdst[i]), 16, 0, 0);
        gsrc[i] += 32;
      }
    }
    // 32 MFMA; compiler inserts counted lgkm waits per fragment group
    __builtin_amdgcn_s_setprio(1);
#pragma unroll
    for (int im = 0; im < 4; ++im)
#pragma unroll
      for (int in = 0; in < 2; ++in)
        acc[im][in] = __builtin_amdgcn_mfma_f32_16x16x32_bf16(a0[im], bf0[in], acc[im][in], 0, 0, 0);
#pragma unroll
    for (int im = 0; im < 4; ++im)
#pragma unroll
      for (int in = 0; in < 2; ++in)
        acc[im][2 + in] = __builtin_amdgcn_mfma_f32_16x16x32_bf16(a0[im], bf1[in], acc[im][2 + in], 0, 0, 0);
#pragma unroll
    for (int im = 0; im < 4; ++im)
#pragma unroll
      for (int in = 0; in < 2; ++in)
        acc[4 + im][2 + in] = __builtin_amdgcn_mfma_f32_16x16x32_bf16(a1[im], bf1[in], acc[4 + im][2 + in], 0, 0, 0);
#pragma unroll
    for (int im = 0; im < 4; ++im)
#pragma unroll
      for (int in = 0; in < 2; ++in)
        acc[4 + im][in] = __builtin_amdgcn_mfma_f32_16x16x32_bf16(a1[im], bf0[in], acc[4 + im][in], 0, 0, 0);
    __builtin_amdgcn_s_setprio(0);

    if (t + 1 < NT) {
      __builtin_amdgcn_sched_barrier(0);
      if (t + 2 < NT) asm volatile("s_waitcnt vmcnt(4)" ::: "memory");
      else            asm volatile("s_waitcnt vmcnt(0)" ::: "memory");
      __builtin_amdgcn_sched_barrier(0);
      __builtin_amdgcn_s_barrier();
      __builtin_amdgcn_sched_barrier(0);
    }
    const int tmp = sb0; sb0 = sb1; sb1 = sb2; sb2 = tmp;
  }

  // epilogue: C/D layout col=lane&15, row=lquad*4+reg (m89/m91)
#pragma unroll
  for (int in = 0; in < 4; ++in) {
    const int col = n0 + wn + in * 16 + lrow;
    const float bb = bias ? bias[col] : 0.0f;
#pragma unroll
    for (int im = 0; im < 8; ++im) {
#pragma unroll
      for (int r = 0; r < 4; ++r) {
        const int row = m0 + wm + im * 16 + lquad * 4 + r;
        const float v = acc[im][in][r] + bb;
        if (MODE == 1) {
          (((u16*)outp) + zstride * z)[(long long)row * ldo + col] = f2bf(v);
        } else if (MODE == 2) {
          ((float*)outp)[(long long)row * ldo + col] += v;
        } else {  // MODE 4
          const long long off = (long long)row * ldo + col;
          const float nv = ((float*)outp)[off] + v;
          ((float*)outp)[off] = nv;
          ((u16*)zstride)[off] = f2bf(nv);
        }
      }
    }
  }
}

// ---------------------------------------------------------------------------
// GEMM (R3/R7 128^2 structure): out[m,n] = sum_k A[m,k]*B[n,k]. Used for the
// first conv GEMM (K=192), MLP, decode scatter, and the small-ws fallback.
// ---------------------------------------------------------------------------
template <int MODE>
__global__ __launch_bounds__(256) void gemm_bt(
    const u16* __restrict__ A, int lda,
    const u16* __restrict__ B0, const u16* __restrict__ B1, const u16* __restrict__ B2,
    int ldb, int K, int NX,
    void* __restrict__ outp, long long zstride, int ldo,
    const float* __restrict__ bias)
{
  __shared__ __align__(16) u16 As[8192];   // 16KB: [t][128][32]
  __shared__ __align__(16) u16 Bs[8192];   // 16KB

  const int l = blockIdx.x;
  const int xcd = l & 7;
  const int j = l >> 3;
  const int per_epoch = 9 * NX;
  const int z = j / per_epoch;
  const int r2 = j - z * per_epoch;
  const int g = r2 / NX;
  const int y = xcd + 8 * g;
  if (y >= 68) return;                      // dead block (uniform) — exits before barriers
  const int x = r2 - g * NX;
  const int n0 = x * 128;
  const int m0 = y * 128;
  const u16* __restrict__ B = (z == 0) ? B0 : ((z == 1) ? B1 : B2);

  const int tid  = threadIdx.x;
  const int wave = tid >> 6;
  const int lane = tid & 63;
  const int wm   = (wave >> 1) * 64;
  const int wn   = (wave & 1) * 64;
  const int lrow = lane & 15;
  const int lquad = lane >> 4;

  facc4 acc[4][4] = {};

  const u16* ga[4]; const u16* gb[4];
#pragma unroll
  for (int j2 = 0; j2 < 4; ++j2) {
    const int s = tid + 256 * j2;
    const int t = s >> 9, s2 = s & 511;
    const int r = s2 >> 2, c = (s2 & 3) + 4 * t;
    ga[j2] = A + (long long)(m0 + r) * lda + c * 8;
    gb[j2] = B + (long long)(n0 + r) * ldb + c * 8;
  }

  const int aoff = (wm + lrow) * 32 + lquad * 8;
  const int boff = (wn + lrow) * 32 + lquad * 8;

  for (int k0 = 0; k0 < K; k0 += 64) {
#pragma unroll
    for (int j2 = 0; j2 < 4; ++j2) {
      __builtin_amdgcn_global_load_lds((const __attribute__((address_space(1))) void*)ga[j2],
                                       (__attribute__((address_space(3))) void*)(As + (tid + 256 * j2) * 8), 16, 0, 0);
      __builtin_amdgcn_global_load_lds((const __attribute__((address_space(1))) void*)gb[j2],
                                       (__attribute__((address_space(3))) void*)(Bs + (tid + 256 * j2) * 8), 16, 0, 0);
      ga[j2] += 64; gb[j2] += 64;
    }
    __syncthreads();

#pragma unroll
    for (int t = 0; t < 2; ++t) {
      bfrag8 af[4], bfr[4];
#pragma unroll
      for (int im = 0; im < 4; ++im) af[im] = *(const bfrag8*)(As + t * 4096 + aoff + 512 * im);
#pragma unroll
      for (int in = 0; in < 4; ++in) bfr[in] = *(const bfrag8*)(Bs + t * 4096 + boff + 512 * in);
#pragma unroll
      for (int im = 0; im < 4; ++im)
#pragma unroll
        for (int in = 0; in < 4; ++in)
          acc[im][in] = __builtin_amdgcn_mfma_f32_16x16x32_bf16(af[im], bfr[in], acc[im][in], 0, 0, 0);
    }
    __syncthreads();
  }

#pragma unroll
  for (int in = 0; in < 4; ++in) {
    const int col = n0 + wn + in * 16 + lrow;
    const float bb = bias ? bias[col] : 0.0f;
#pragma unroll
    for (int im = 0; im < 4; ++im) {
#pragma unroll
      for (int r = 0; r < 4; ++r) {
        const int row = m0 + wm + im * 16 + lquad * 4 + r;
        const float v = acc[im][in][r] + bb;
        if (MODE == 0) {
          ((float*)outp)[(long long)row * ldo + col] = v;
        } else if (MODE == 1) {
          (((u16*)outp) + zstride * z)[(long long)row * ldo + col] = f2bf(v);
        } else if (MODE == 2) {
          ((float*)outp)[(long long)row * ldo + col] += v;
        } else if (MODE == 4) {
          const long long off = (long long)row * ldo + col;
          const float nv = ((float*)outp)[off] + v;
          ((float*)outp)[off] = nv;
          ((u16*)zstride)[off] = f2bf(nv);
        } else {  // MODE 3: deconv scatter. row=b*17+s, col=d*49+hk*7+wk (<147)
          if (col < 147) {
            const int b = row / 17, s = row - b * 17;
            const int d = col / 49, rem = col - d * 49;
            const int hk = rem / 7, wk = rem - hk * 7;
            ((float*)outp)[(long long)((b * 3 + d) * 7 + hk) * 119 + s * 7 + wk] = v;
          }
        }
      }
    }
  }
}

// ---------------------------------------------------------------------------
// LayerNorm over C=1024: fp32 h row -> bf16 normalized row. float4/ushort4.
// ---------------------------------------------------------------------------
__global__ __launch_bounds__(256) void ln_kernel(
    const float* __restrict__ h, const float* __restrict__ w,
    const float* __restrict__ b, u16* __restrict__ out)
{
  const long long row = blockIdx.x;
  const int t = threadIdx.x;
  const float4 v = ((const float4*)(h + row * 1024))[t];
  float s = v.x + v.y + v.z + v.w;
  float q = v.x * v.x + v.y * v.y + v.z * v.z + v.w * v.w;
  for (int o = 32; o > 0; o >>= 1) { s += __shfl_down(s, o); q += __shfl_down(q, o); }
  __shared__ float ss[4], sq[4];
  const int wave = t >> 6, lane = t & 63;
  if (lane == 0) { ss[wave] = s; sq[wave] = q; }
  __syncthreads();
  const float st = ss[0] + ss[1] + ss[2] + ss[3];
  const float qt = sq[0] + sq[1] + sq[2] + sq[3];
  const float mean = st * (1.0f / 1024.0f);
  const float var = qt * (1.0f / 1024.0f) - mean * mean;
  const float inv = rsqrtf(var + 1e-5f);
  const float4 w4 = ((const float4*)w)[t];
  const float4 b4 = ((const float4*)b)[t];
  ushort4 o;
  o.x = f2bf((v.x - mean) * inv * w4.x + b4.x);
  o.y = f2bf((v.y - mean) * inv * w4.y + b4.y);
  o.z = f2bf((v.z - mean) * inv * w4.z + b4.z);
  o.w = f2bf((v.w - mean) * inv * w4.w + b4.w);
  ((ushort4*)(out + row * 1024))[t] = o;
}

// ---------------------------------------------------------------------------
// Causal attention, T=17, hd=64. One block per (batch, head). h += attn out.
// ---------------------------------------------------------------------------
__global__ __launch_bounds__(256) void attn_kernel(const u16* __restrict__ QKV,
                                                   float* __restrict__ h)
{
  const int blk = blockIdx.x;          // 0..8191
  const int b = blk >> 4, head = blk & 15;
  __shared__ float qs[17][64], ks[17][64], vs[17][64];
  __shared__ float sc[17][20];
  const long long base = (long long)b * 17408 + head * 64;   // 17*1024
  const u16* Q  = QKV;
  const u16* Kp = QKV + 8912896LL;       // 8704*1024
  const u16* V  = QKV + 17825792LL;
  const int tid = threadIdx.x;

  if (tid < 136) {                        // 17 rows x 8 chunks of 8 bf16
    const int t = tid >> 3, dg = (tid & 7) * 8;
    const long long off = base + (long long)t * 1024 + dg;
    union { uint4 u; u16 s[8]; } xq, xk, xv;
    xq.u = *(const uint4*)(Q + off);
    xk.u = *(const uint4*)(Kp + off);
    xv.u = *(const uint4*)(V + off);
#pragma unroll
    for (int j = 0; j < 8; ++j) {
      qs[t][dg + j] = bf2f(xq.s[j]);
      ks[t][dg + j] = bf2f(xk.s[j]);
      vs[t][dg + j] = bf2f(xv.s[j]);
    }
  }
  __syncthreads();

  for (int i = tid; i < 289; i += 256) {
    const int tq = i / 17, tk = i % 17;
    float a = 0.0f;
    if (tk <= tq) {
#pragma unroll
      for (int d = 0; d < 64; ++d) a += qs[tq][d] * ks[tk][d];
      a *= 0.125f;                     // 1/sqrt(64)
    }
    sc[tq][tk] = a;
  }
  __syncthreads();

  if (tid < 17) {
    const int tq = tid;
    float m = -1e30f;
    for (int tk = 0; tk <= tq; ++tk) m = fmaxf(m, sc[tq][tk]);
    float s = 0.0f;
    for (int tk = 0; tk <= tq; ++tk) { const float e = __expf(sc[tq][tk] - m); sc[tq][tk] = e; s += e; }
    const float inv = 1.0f / s;
    for (int tk = 0; tk <= tq; ++tk) sc[tq][tk] *= inv;
  }
  __syncthreads();

  for (int i = tid; i < 272; i += 256) {  // 17 rows x 16 float4 groups (loop!)
    const int tq = i >> 4, dg = (i & 15) * 4;
    float o0 = 0, o1 = 0, o2 = 0, o3 = 0;
    for (int tk = 0; tk <= tq; ++tk) {
      const float s = sc[tq][tk];
      o0 += s * vs[tk][dg];     o1 += s * vs[tk][dg + 1];
      o2 += s * vs[tk][dg + 2]; o3 += s * vs[tk][dg + 3];
    }
    float4* hp = (float4*)(h + base + (long long)tq * 1024 + dg);
    float4 hv = *hp;
    hv.x += o0; hv.y += o1; hv.z += o2; hv.w += o3;
    *hp = hv;                             // exclusive owner of this slice
  }
}

// ---------------------------------------------------------------------------
// Build patch matrix P bf16 [8704][192]; t=0 thumb = 2x2 avg (bilinear scale-4
// half-pixel), t=1+s patch; cols 147..191 zero-pad (K padded to 192).
// ---------------------------------------------------------------------------
__global__ void build_p(const float* __restrict__ x, u16* __restrict__ P)
{
  const int n = blockIdx.x;
  const int j = threadIdx.x;
  if (j >= 192) return;
  const int b = n / 17, t = n % 17;
  float val = 0.0f;
  if (j < 147) {
    const int c = j / 49, rem = j % 49, p = rem / 7, q = rem % 7;
    const float* xb = x + (long long)(b * 3 + c) * 784;
    if (t == 0) {
      const int r = 4 * p + 1, cc = 4 * q + 1;
      val = 0.25f * (xb[r * 28 + cc] + xb[r * 28 + cc + 1] +
                     xb[(r + 1) * 28 + cc] + xb[(r + 1) * 28 + cc + 1]);
    } else {
      const int s = t - 1, ii = s >> 2, jj = s & 3;
      val = xb[(7 * ii + p) * 28 + 7 * jj + q];
    }
  }
  P[(long long)n * 192 + j] = f2bf(val);
}

// conv_w fp32 [1024][147] -> Wc bf16 [1024][192] (zero-pad K to 192) and
// cw2 bf16 [256][1024]: cw2[j][c] = conv_w[c*147+j], rows 147..255 zero.
__global__ __launch_bounds__(256) void cvt_conv(const float* __restrict__ cw,
                                                u16* __restrict__ Wc, u16* __restrict__ cw2)
{
  const int i = blockIdx.x * 256 + threadIdx.x;     // grid covers 196608 + 262144
  if (i < 196608) {
    const int d = i / 192, j = i % 192;
    Wc[i] = (j < 147) ? f2bf(cw[d * 147 + j]) : (u16)0;
  } else {
    const int i2 = i - 196608;
    if (i2 < 262144) {
      const int j = i2 / 1024, c = i2 % 1024;
      cw2[i2] = (j < 147) ? f2bf(cw[c * 147 + j]) : (u16)0;
    }
  }
}

// W'[j][k] = sum_c cw2[j][c] * outw[c][k]  (fused out-proj+deconv weight).
__global__ __launch_bounds__(256) void wprime_kernel(
    const u16* __restrict__ cw2, const float* __restrict__ outw,
    u16* __restrict__ Wp)
{
  const int k = blockIdx.x * 256 + threadIdx.x;
  const int j = blockIdx.y;
  float a = 0.0f;
  for (int c = 0; c < 1024; ++c)
    a += bf2f(cw2[j * 1024 + c]) * outw[c * 1024 + k];
  Wp[j * 1024 + k] = f2bf(a);
}

// b'[j] = sum_c outb[c] * cw2[j][c]. One block, 256 threads.
__global__ __launch_bounds__(256) void bprime_kernel(
    const u16* __restrict__ cw2, const float* __restrict__ outb,
    float* __restrict__ bp)
{
  const int j = threadIdx.x;
  float a = 0.0f;
  for (int c = 0; c < 1024; ++c) a += outb[c] * bf2f(cw2[j * 1024 + c]);
  bp[j] = a;
}

// Bulk weight convert: 49 x 1M fp32 -> bf16.
__global__ __launch_bounds__(256) void cvt_all(
    const float* __restrict__ wq, const float* __restrict__ wk,
    const float* __restrict__ wv, const float* __restrict__ mlpw,
    const float* __restrict__ outw, u16* __restrict__ wAll)
{
  const int i = blockIdx.x * 256 + threadIdx.x;    // float4 index, < 12,845,056
  const int which = i >> 18;                        // 0..48
  const int off = i & 262143;
  const float4* src;
  if (which < 48) {
    const int layer = which >> 2, sub = which & 3;
    const float* base = (sub == 0) ? wq : (sub == 1) ? wk : (sub == 2) ? wv : mlpw;
    src = (const float4*)(base + (size_t)layer * 1048576) + off;
  } else {
    src = (const float4*)outw + off;
  }
  const float4 v = *src;
  ushort4 o; o.x = f2bf(v.x); o.y = f2bf(v.y); o.z = f2bf(v.z); o.w = f2bf(v.w);
  *(ushort4*)(wAll + (size_t)which * 1048576 + (size_t)off * 4) = o;
}

// per-layer weight cast fallback (small ws): wq,wk,wv -> o3[3][1M], mlp -> om.
__global__ __launch_bounds__(256) void cvt4(const float* __restrict__ a0, const float* __restrict__ a1,
                                            const float* __restrict__ a2, const float* __restrict__ a3,
                                            u16* __restrict__ o3, u16* __restrict__ om)
{
  const int i = blockIdx.x * 256 + threadIdx.x;
  const int which = i >> 20, off = i & 1048575;
  const float* src = (which == 0) ? a0 : (which == 1) ? a1 : (which == 2) ? a2 : a3;
  const float v = src[off];
  if (which < 3) o3[which * 1048576 + off] = f2bf(v);
  else           om[off] = f2bf(v);
}

__global__ __launch_bounds__(256) void cvtN(const float* __restrict__ in, u16* __restrict__ out, int n)
{
  const int i = blockIdx.x * 256 + threadIdx.x;
  if (i < n) out[i] = f2bf(in[i]);
}

// ---------------------------------------------------------------------------
extern "C" void kernel_launch(void* const* d_in, const int* in_sizes, int n_in,
                              void* d_out, int out_size, void* d_ws, size_t ws_size,
                              hipStream_t stream)
{
  const float* x     = (const float*)d_in[0];
  const float* convw = (const float*)d_in[1];
  const float* ln1w  = (const float*)d_in[2];
  const float* ln1b  = (const float*)d_in[3];
  const float* wq    = (const float*)d_in[4];
  const float* wk    = (const float*)d_in[5];
  const float* wv    = (const float*)d_in[6];
  const float* ln2w  = (const float*)d_in[7];
  const float* ln2b  = (const float*)d_in[8];
  const float* mlpw  = (const float*)d_in[9];
  const float* mlpb  = (const float*)d_in[10];
  const float* outw  = (const float*)d_in[11];
  const float* outb  = (const float*)d_in[12];

  char* w = (char*)d_ws;
  const bool big = (ws_size >= 214500352ULL);

  // old-kernel grid sizes: 8 xcd * NZ * 9 groups * NX
  const int G_QKV = 8 * 3 * 9 * 8;   // 1728 (fallback path)
  const int G_ONE = 8 * 1 * 9 * 8;   // 576
  const int G_DEC = 8 * 1 * 9 * 2;   // 144

  if (big) {
    float* h   = (float*)(w);                   // 35,651,584 B
    u16* Abuf  = (u16*)(w + 35651584);          // 17,825,792 B
    u16* QKV   = (u16*)(w + 53477376);          // 53,477,376 B (dead after last attn
                                                //   -> reused as bf16 h-shadow)
    u16* wAll  = (u16*)(w + 106954752);         // 102,760,448 B (49 x 1M bf16)
    u16* Wc    = (u16*)(w + 209715200);         //    393,216 B
    u16* cw2   = (u16*)(w + 210108416);         //    524,288 B
    u16* P     = (u16*)(w + 210632704);         //  3,342,336 B
    u16* Wp    = (u16*)(w + 213975040);         //    524,288 B
    float* bp  = (float*)(w + 214499328);       //      1,024 B -> 214,500,352

    cvt_all<<<50176, 256, 0, stream>>>(wq, wk, wv, mlpw, outw, wAll);
    cvt_conv<<<1792, 256, 0, stream>>>(convw, Wc, cw2);
    wprime_kernel<<<dim3(4, 256), 256, 0, stream>>>(cw2, outw, Wp);
    bprime_kernel<<<1, 256, 0, stream>>>(cw2, outb, bp);
    build_p<<<8704, 192, 0, stream>>>(x, P);
    gemm_bt<0><<<G_ONE, 256, 0, stream>>>(P, 192, Wc, Wc, Wc, 192, 192, 8,
                                          (void*)h, 0LL, 1024, nullptr);
    for (int l = 0; l < 12; ++l) {
      u16* wl = wAll + (size_t)l * 4194304;
      ln_kernel<<<8704, 256, 0, stream>>>(h, ln1w + l * 1024, ln1b + l * 1024, Abuf);
      // QKV: 34 M-tiles x 4 N-tiles x 3 weights = 408 blocks = 8*51
      gemm256<1><<<408, 512, 0, stream>>>(Abuf, 1024, wl, wl + 1048576, wl + 2097152,
                                          1024, 1024, 51, (void*)QKV, 8912896LL, 1024, nullptr);
      attn_kernel<<<8192, 256, 0, stream>>>(QKV, h);
      ln_kernel<<<8704, 256, 0, stream>>>(h, ln2w + l * 1024, ln2b + l * 1024, Abuf);
      if (l < 11) {
        gemm_bt<2><<<G_ONE, 256, 0, stream>>>(Abuf, 1024, wl + 3145728, wl, wl,
                                              1024, 1024, 8, (void*)h, 0LL, 1024, mlpb + l * 1024);
      } else {  // last MLP: h += v AND bf16 shadow into QKV (dead; NOT an input)
        gemm_bt<4><<<G_ONE, 256, 0, stream>>>(Abuf, 1024, wl + 3145728, wl, wl,
                                              1024, 1024, 8, (void*)h,
                                              (long long)(uintptr_t)QKV, 1024,
                                              mlpb + l * 1024);
      }
    }
    // fused out-proj+decode: d_out = scatter(h_bf16 @ W'^T + b')
    gemm_bt<3><<<G_DEC, 256, 0, stream>>>(QKV, 1024, Wp, Wp, Wp,
                                          1024, 1024, 2, d_out, 0LL, 0, bp);
  } else {
    if (ws_size < 119603200ULL) return;
    float* h   = (float*)(w);
    u16* Abuf  = (u16*)(w + 35651584);
    u16* QKV   = (u16*)(w + 53477376);
    u16* wb3   = (u16*)(w + 106954752);          // 6,291,456
    u16* wmb   = (u16*)(w + 113246208);          // 2,097,152
    u16* Wc    = (u16*)(w + 115343360);          //   393,216
    u16* cw2   = (u16*)(w + 115736576);          //   524,288
    u16* P     = (u16*)(w + 116260864);          // 3,342,336 -> 119,603,200

    cvt_conv<<<1792, 256, 0, stream>>>(convw, Wc, cw2);
    build_p<<<8704, 192, 0, stream>>>(x, P);
    gemm_bt<0><<<G_ONE, 256, 0, stream>>>(P, 192, Wc, Wc, Wc, 192, 192, 8,
                                          (void*)h, 0LL, 1024, nullptr);
    for (int l = 0; l < 12; ++l) {
      const size_t wo = (size_t)l * 1048576;
      cvt4<<<16384, 256, 0, stream>>>(wq + wo, wk + wo, wv + wo, mlpw + wo, wb3, wmb);
      ln_kernel<<<8704, 256, 0, stream>>>(h, ln1w + l * 1024, ln1b + l * 1024, Abuf);
      gemm_bt<1><<<G_QKV, 256, 0, stream>>>(Abuf, 1024, wb3, wb3 + 1048576, wb3 + 2097152,
                                            1024, 1024, 8, (void*)QKV, 8912896LL, 1024, nullptr);
      attn_kernel<<<8192, 256, 0, stream>>>(QKV, h);
      ln_kernel<<<8704, 256, 0, stream>>>(h, ln2w + l * 1024, ln2b + l * 1024, Abuf);
      gemm_bt<2><<<G_ONE, 256, 0, stream>>>(Abuf, 1024, wmb, wmb, wmb,
                                            1024, 1024, 8, (void*)h, 0LL, 1024, mlpb + l * 1024);
    }
    cvtN<<<34816, 256, 0, stream>>>(h, Abuf, 8912896);
    cvtN<<<4096, 256, 0, stream>>>(outw, wmb, 1048576);
    gemm_bt<1><<<G_ONE, 256, 0, stream>>>(Abuf, 1024, wmb, wmb, wmb,
                                          1024, 1024, 8, (void*)QKV, 0LL, 1024, outb);
    gemm_bt<3><<<G_DEC, 256, 0, stream>>>(QKV, 1024, cw2, cw2, cw2,
                                          1024, 1024, 2, d_out, 0LL, 0, nullptr);
  }
}